// Round 21
// baseline (130.302 us; speedup 1.0000x reference)
//
#include <hip/hip_runtime.h>
#include <hip/hip_bf16.h>

#define BB 2
#define SS 2048
#define EE 1024
#define HH 16
#define DD 64
#define MM (BB*SS)      // 4096
#define N1 (3*EE)       // 3072

typedef __attribute__((ext_vector_type(4))) float f32x4;
typedef __attribute__((ext_vector_type(16))) float f32x16;
typedef __attribute__((ext_vector_type(8))) short bf16x8;
typedef __attribute__((ext_vector_type(4))) unsigned int u32x4;
typedef __attribute__((ext_vector_type(2))) unsigned int u32x2;

__device__ __forceinline__ ushort f2bf(float f){
  union { float f; unsigned u; } v; v.f = f;
  unsigned r = v.u + 0x7fffu + ((v.u >> 16) & 1u);
  return (ushort)(r >> 16);
}

__device__ __forceinline__ float bf2f(ushort u){
  union { unsigned u; float f; } v; v.u = ((unsigned)u) << 16; return v.f;
}

__device__ __forceinline__ unsigned cvt_pk(float a, float b){
  unsigned r; asm("v_cvt_pk_bf16_f32 %0, %1, %2" : "=v"(r) : "v"(a), "v"(b)); return r;
}

__device__ __forceinline__ float exp2_fast(float x){
  float r; asm("v_exp_f32 %0, %1" : "=v"(r) : "v"(x)); return r;
}

// v_permlane32_swap_b32 (lane-half exchange of 32-bit values)
__device__ __forceinline__ u32x2 pl32swap(unsigned a, unsigned b){
  return __builtin_amdgcn_permlane32_swap(a, b, false, false);
}

// async global->LDS, 16B per lane. LDS dest = wave-uniform base + lane*16.
__device__ __forceinline__ void gload16(const void* g, void* l){
  __builtin_amdgcn_global_load_lds(
      (const __attribute__((address_space(1))) unsigned*)g,
      (__attribute__((address_space(3))) unsigned*)l, 16, 0, 0);
}

// ---- prep: weight transposes only (x conversion folded into gemm_qkv).
// blocks 0..3071 -> w_attn^T; 3072..4095 -> w_proj^T.
__global__ __launch_bounds__(256) void prep_kernel(
    const float* __restrict__ wa, ushort* __restrict__ waT,
    const float* __restrict__ wp, ushort* __restrict__ wpT){
  __shared__ float t[32][33];
  const int bid = blockIdx.x, tid = threadIdx.x;
  const float* in; ushort* out; int N, nx, b;
  if (bid < 3072){ b = bid;        in = wa; out = waT; N = N1; nx = N1/32; }
  else           { b = bid - 3072; in = wp; out = wpT; N = EE; nx = EE/32; }
  const int n0 = (b % nx)*32, k0 = (b / nx)*32;
  const int tx = tid & 31, ty = tid >> 5;
  for (int r = ty; r < 32; r += 8)
    t[r][tx] = in[(size_t)(k0+r)*N + n0 + tx];
  __syncthreads();
  for (int r = ty; r < 32; r += 8)
    out[(size_t)(n0+r)*EE + k0 + tx] = f2bf(t[tx][r]);
}

// ---- QKV GEMM, 128x128 tile, BK=64 + XOR-swizzled LDS (round-12/18 proven).
// A is staged DIRECTLY from fp32 x: 2x float4 load -> v_cvt_pk_bf16_f32 ->
// ds_write_b128 into the same linear LDS slot gload16 used (stride-1 writes,
// conflict-free; read side + swizzle unchanged). Kills the prep x-pass.
// NOTE: 256x128 tile REGRESSED (r13); BK=32 ring-3 counted-vmcnt REGRESSED (r19).
__global__ __launch_bounds__(256) void gemm_qkv(const float* __restrict__ X,
    const ushort* __restrict__ Bt, const float* __restrict__ bias,
    ushort* __restrict__ q_, ushort* __restrict__ k_, ushort* __restrict__ v_,
    int M, int N, int K){
  __shared__ ushort As[128*64];
  __shared__ ushort Bs[128*64];
  const int tid = threadIdx.x;
  const int lane = tid & 63, w = tid >> 6;
  const int nx = gridDim.x;
  const int nwg = nx * gridDim.y;
  const int flat = blockIdx.y*nx + blockIdx.x;
  const int sw = (flat & 7)*(nwg >> 3) + (flat >> 3);
  const int m0 = (sw / nx)*128, n0 = (sw % nx)*128;
  const int wm = (w >> 1)*64, wn = (w & 1)*64;
  const int lr = lane & 15, g4 = lane >> 4;
  const int c0 = w*4;
  const int csr = lane >> 3;
  const int gcb = ((lane & 7) ^ csr)*8;
  const int sw7 = lr & 7;

  f32x4 acc[4][4] = {};
  for (int k0 = 0; k0 < K; k0 += 64){
    #pragma unroll
    for (int i = 0; i < 4; ++i){
      const int c = c0 + i;
      // A: fp32 -> bf16 in-flight (reg-staged)
      const float* xp = X + (size_t)(m0 + c*8 + csr)*K + k0 + gcb;
      const f32x4 f0 = *(const f32x4*)(xp);
      const f32x4 f1 = *(const f32x4*)(xp + 4);
      u32x4 pk;
      pk[0] = cvt_pk(f0[0], f0[1]); pk[1] = cvt_pk(f0[2], f0[3]);
      pk[2] = cvt_pk(f1[0], f1[1]); pk[3] = cvt_pk(f1[2], f1[3]);
      *(u32x4*)&As[(c*8 + csr)*64 + (lane & 7)*8] = pk;
      // B: async direct-to-LDS (bf16 weights)
      gload16(Bt + (size_t)(n0 + c*8 + csr)*K + k0 + gcb, &Bs[(c*8)*64]);
    }
    __syncthreads();
    #pragma unroll
    for (int kk = 0; kk < 2; ++kk){
      bf16x8 af[4], bfr[4];
      #pragma unroll
      for (int m = 0; m < 4; ++m)
        af[m] = *reinterpret_cast<bf16x8*>(&As[(wm + m*16 + lr)*64 + (((kk*4 + g4) ^ sw7)*8)]);
      #pragma unroll
      for (int n = 0; n < 4; ++n)
        bfr[n] = *reinterpret_cast<bf16x8*>(&Bs[(wn + n*16 + lr)*64 + (((kk*4 + g4) ^ sw7)*8)]);
      __builtin_amdgcn_s_setprio(1);
      #pragma unroll
      for (int m = 0; m < 4; ++m)
        #pragma unroll
        for (int n = 0; n < 4; ++n)
          acc[m][n] = __builtin_amdgcn_mfma_f32_16x16x32_bf16(af[m], bfr[n], acc[m][n], 0, 0, 0);
      __builtin_amdgcn_s_setprio(0);
    }
    __syncthreads();
  }
  #pragma unroll
  for (int m = 0; m < 4; ++m){
    #pragma unroll
    for (int n = 0; n < 4; ++n){
      int col = n0 + wn + n*16 + lr;
      float bv = bias[col];
      #pragma unroll
      for (int r = 0; r < 4; ++r){
        int row = m0 + wm + m*16 + (lane >> 4)*4 + r;
        float v = acc[m][n][r] + bv;
        int b = row >> 11, s = row & 2047;
        int h = col / 192, t = col - h*192;
        ushort u = f2bf(v);
        size_t bh = (size_t)(b*HH + h);
        if (t < 64)       q_[(bh*SS + s)*DD + t]        = u;
        else if (t < 128) k_[(bh*SS + s)*DD + (t-64)]   = u;
        else              v_[(bh*DD + (t-128))*SS + s]  = u;
      }
    }
  }
}

// ---- proj GEMM: 64x128 tile, BK=64, XOR-swizzle. 512 blocks -> 2 blocks/CU.
__global__ __launch_bounds__(256) void gemm_proj(const ushort* __restrict__ A,
    const ushort* __restrict__ Bt, const float* __restrict__ bias,
    float* __restrict__ of, int M, int N, int K){
  __shared__ ushort As[64*64];    // 8 KB
  __shared__ ushort Bs[128*64];   // 16 KB
  const int tid = threadIdx.x;
  const int lane = tid & 63, w = tid >> 6;
  const int nx = gridDim.x;                       // 8
  const int nwg = nx * gridDim.y;                 // 512
  const int flat = blockIdx.y*nx + blockIdx.x;
  const int sw = (flat & 7)*(nwg >> 3) + (flat >> 3);
  const int m0 = (sw / nx)*64, n0 = (sw % nx)*128;
  const int lr = lane & 15, g4 = lane >> 4;
  const int csr = lane >> 3;
  const int gcb = ((lane & 7) ^ csr)*8;
  const int sw7 = lr & 7;

  f32x4 acc[4][2] = {};
  for (int k0 = 0; k0 < K; k0 += 64){
    #pragma unroll
    for (int i = 0; i < 2; ++i){                  // A: 8 chunks, 2/wave
      const int c = w*2 + i;
      gload16(A + (size_t)(m0 + c*8 + csr)*K + k0 + gcb, &As[(c*8)*64]);
    }
    #pragma unroll
    for (int i = 0; i < 4; ++i){                  // B: 16 chunks, 4/wave
      const int c = w*4 + i;
      gload16(Bt + (size_t)(n0 + c*8 + csr)*K + k0 + gcb, &Bs[(c*8)*64]);
    }
    __syncthreads();
    #pragma unroll
    for (int kk = 0; kk < 2; ++kk){
      bf16x8 af[4], bfr[2];
      #pragma unroll
      for (int m = 0; m < 4; ++m)
        af[m] = *reinterpret_cast<bf16x8*>(&As[(m*16 + lr)*64 + (((kk*4 + g4) ^ sw7)*8)]);
      #pragma unroll
      for (int n = 0; n < 2; ++n)
        bfr[n] = *reinterpret_cast<bf16x8*>(&Bs[(w*32 + n*16 + lr)*64 + (((kk*4 + g4) ^ sw7)*8)]);
      __builtin_amdgcn_s_setprio(1);
      #pragma unroll
      for (int m = 0; m < 4; ++m)
        #pragma unroll
        for (int n = 0; n < 2; ++n)
          acc[m][n] = __builtin_amdgcn_mfma_f32_16x16x32_bf16(af[m], bfr[n], acc[m][n], 0, 0, 0);
      __builtin_amdgcn_s_setprio(0);
    }
    __syncthreads();
  }
  #pragma unroll
  for (int m = 0; m < 4; ++m){
    #pragma unroll
    for (int n = 0; n < 2; ++n){
      int col = n0 + w*32 + n*16 + lr;
      float bv = bias[col];
      #pragma unroll
      for (int r = 0; r < 4; ++r){
        int row = m0 + m*16 + g4*4 + r;
        of[(size_t)row*N + col] = acc[m][n][r] + bv;
      }
    }
  }
}

// ---- causal flash attention, split-K x2 + no-max softmax, ring-3 + vmcnt(4)
// (round-12/16 proven config; r20 XCD remap kept — neutral-to-positive.)
#define SCL 0.18033688f          /* log2(e)/8 */
__global__ __launch_bounds__(256,3) void attn2(const ushort* __restrict__ Qg,
    const ushort* __restrict__ Kg, const ushort* __restrict__ Vg,
    ushort* __restrict__ aout, ushort* __restrict__ pbuf,
    float* __restrict__ s0b, float* __restrict__ s1b){
  __shared__ __align__(16) ushort Kl[3][64*64];
  __shared__ __align__(16) ushort Vl[3][64*64];
  const int tid = threadIdx.x, lane = tid & 63, wv = tid >> 6;
  // XCD swizzle: flat id -> logical so XCD r (= flat%8) owns bh [4r, 4r+4)
  const int flat = blockIdx.y*32 + blockIdx.x;        // 0..767
  const int logical = (flat & 7)*96 + (flat >> 3);    // bijective (768 = 8*96)
  const int bh = logical / 24;
  const int c  = logical - bh*24;
  int qt, t0, t1, half;
  if (c < 8){ qt = c; t0 = 0; t1 = 2*(c+1); half = -1; }
  else { int i = c - 8; qt = 8 + (i >> 1); int n = qt + 1; half = i & 1;
         t0 = half ? n : 0; t1 = half ? 2*n : n; }
  const int b = bh >> 4, h = bh & 15;
  const int q0 = qt*128;
  const int ql = lane & 31, g = lane >> 5;
  const int qrow = q0 + wv*32 + ql;
  const int qminw = q0 + wv*32;
  const int qmaxw = qminw + 31;

  const ushort* Qp = Qg + ((size_t)bh*SS + qrow)*DD;
  bf16x8 qf[4];
  #pragma unroll
  for (int s = 0; s < 4; ++s)
    qf[s] = *(const bf16x8*)(Qp + s*16 + g*8);

  f32x16 ot[2] = {};
  float sr = 0.f;

  const int csr = lane >> 3;
  const int gcb = ((lane & 7) ^ csr)*8;
  const ushort* Kbase = Kg + (size_t)bh*SS*DD;
  const ushort* Vbase = Vg + (size_t)bh*DD*SS;
  const int nv = (qmaxw >> 6) + 1;
  const int swq = (ql & 7);

  auto stage = [&](int t, int bi){          // 4 loads/wave
    const int k0 = t*64;
    #pragma unroll
    for (int i = 0; i < 2; ++i){
      const int ch = wv*2 + i;
      gload16(Kbase + (size_t)(k0 + ch*8 + csr)*DD + gcb, &Kl[bi][(ch*8)*64]);
      gload16(Vbase + (size_t)(ch*8 + csr)*SS + k0 + gcb, &Vl[bi][(ch*8)*64]);
    }
  };

  auto qk = [&](int t, int bi, f32x16& s0, f32x16& s1){
    const ushort* Kc = &Kl[bi][0];
    f32x16 a0 = {}, a1 = {};
    __builtin_amdgcn_s_setprio(1);
    #pragma unroll
    for (int s = 0; s < 4; ++s){
      bf16x8 kf0 = *(const bf16x8*)&Kc[ ql     *64 + (((2*s + g) ^ swq)*8)];
      bf16x8 kf1 = *(const bf16x8*)&Kc[(32+ql) *64 + (((2*s + g) ^ swq)*8)];
      a0 = __builtin_amdgcn_mfma_f32_32x32x16_bf16(kf0, qf[s], a0, 0, 0, 0);
      a1 = __builtin_amdgcn_mfma_f32_32x32x16_bf16(kf1, qf[s], a1, 0, 0, 0);
    }
    __builtin_amdgcn_s_setprio(0);
    const int k0 = t*64;
    if (k0 + 63 > qminw){
      #pragma unroll
      for (int r = 0; r < 16; ++r){
        int kg0 = k0 + (r & 3) + 8*(r >> 2) + 4*g;
        a0[r] = (kg0 > qrow) ? -1e30f : a0[r];
        a1[r] = (kg0 + 32 > qrow) ? -1e30f : a1[r];
      }
    }
    s0 = a0; s1 = a1;
  };

  auto smpv = [&](int bi, f32x16& s0, f32x16& s1){
    float p[2][16];
    #pragma unroll
    for (int r = 0; r < 16; ++r){
      p[0][r] = exp2_fast(s0[r]*SCL);
      p[1][r] = exp2_fast(s1[r]*SCL);
    }
    float s8[8];
    #pragma unroll
    for (int i = 0; i < 8; ++i)
      s8[i] = (p[0][i] + p[0][i+8]) + (p[1][i] + p[1][i+8]);
    float ts = ((s8[0]+s8[1]) + (s8[2]+s8[3])) + ((s8[4]+s8[5]) + (s8[6]+s8[7]));
    { u32x2 rs = pl32swap(__float_as_uint(ts), __float_as_uint(ts));
      ts = __uint_as_float(rs[0]) + __uint_as_float(rs[1]); }
    sr += ts;

    const ushort* Vc = &Vl[bi][0];
    __builtin_amdgcn_s_setprio(1);
    #pragma unroll
    for (int kf = 0; kf < 2; ++kf){
      #pragma unroll
      for (int s2 = 0; s2 < 2; ++s2){
        const int base = s2*8;
        unsigned u0 = cvt_pk(p[kf][base+0], p[kf][base+1]);
        unsigned u1 = cvt_pk(p[kf][base+2], p[kf][base+3]);
        unsigned u2 = cvt_pk(p[kf][base+4], p[kf][base+5]);
        unsigned u3 = cvt_pk(p[kf][base+6], p[kf][base+7]);
        u32x2 r0 = pl32swap(u0, u2);
        u32x2 r1 = pl32swap(u1, u3);
        union { u32x4 u; bf16x8 hv; } pw;
        pw.u[0] = r0[0]; pw.u[1] = r1[0]; pw.u[2] = r0[1]; pw.u[3] = r1[1];
        const int cbv = 4*kf + 2*s2 + g;
        bf16x8 v0f = *(const bf16x8*)&Vc[ ql     *64 + ((cbv ^ swq)*8)];
        bf16x8 v1f = *(const bf16x8*)&Vc[(32+ql) *64 + ((cbv ^ swq)*8)];
        ot[0] = __builtin_amdgcn_mfma_f32_32x32x16_bf16(v0f, pw.hv, ot[0], 0, 0, 0);
        ot[1] = __builtin_amdgcn_mfma_f32_32x32x16_bf16(v1f, pw.hv, ot[1], 0, 0, 0);
      }
    }
    __builtin_amdgcn_s_setprio(0);
  };

  stage(t0, 0);
  stage(t0 + 1, 1);
  int bi = 0;                               // buffer of tile t: (t - t0) % 3
  for (int t = t0; t < t1; ++t){
    if (t + 1 < t1) { asm volatile("s_waitcnt vmcnt(4)" ::: "memory"); }
    else            { asm volatile("s_waitcnt vmcnt(0)" ::: "memory"); }
    __builtin_amdgcn_s_barrier();
    __builtin_amdgcn_sched_barrier(0);
    if (t + 2 < t1){
      int bs = bi + 2; if (bs >= 3) bs -= 3;
      stage(t + 2, bs);
    }
    if (t < nv){
      f32x16 s0, s1;
      qk(t, bi, s0, s1);
      smpv(bi, s0, s1);
    }
    ++bi; if (bi == 3) bi = 0;
  }

  const float inv = 1.f / sr;
  if (half == 1){
    const int pr = ((qt - 8)*32 + bh)*128 + wv*32 + ql;
    #pragma unroll
    for (int df = 0; df < 2; ++df){
      #pragma unroll
      for (int t = 0; t < 4; ++t){
        ushort4 o4;
        o4.x = f2bf(ot[df][t*4+0]*inv);
        o4.y = f2bf(ot[df][t*4+1]*inv);
        o4.z = f2bf(ot[df][t*4+2]*inv);
        o4.w = f2bf(ot[df][t*4+3]*inv);
        int d = df*32 + 8*t + 4*g;
        *(ushort4*)&pbuf[(size_t)pr*64 + d] = o4;
      }
    }
    if (g == 0) s1b[pr] = sr;
  } else {
    const size_t obase = ((size_t)b*SS + qrow)*EE + h*DD;
    #pragma unroll
    for (int df = 0; df < 2; ++df){
      #pragma unroll
      for (int t = 0; t < 4; ++t){
        ushort4 o4;
        o4.x = f2bf(ot[df][t*4+0]*inv);
        o4.y = f2bf(ot[df][t*4+1]*inv);
        o4.z = f2bf(ot[df][t*4+2]*inv);
        o4.w = f2bf(ot[df][t*4+3]*inv);
        int d = df*32 + 8*t + 4*g;
        *(ushort4*)&aout[obase + d] = o4;
      }
    }
    if (half == 0){
      const int pr = ((qt - 8)*32 + bh)*128 + wv*32 + ql;
      if (g == 0) s0b[pr] = sr;
    }
  }
}

// ---- merge split-K halves: O = (s0*O0 + s1*O1)/(s0+s1) for qt 8..15 ----
__global__ __launch_bounds__(256) void combine_kernel(ushort* __restrict__ ab,
    const ushort* __restrict__ pbuf, const float* __restrict__ s0b,
    const float* __restrict__ s1b){
  const int idx = blockIdx.x*256 + threadIdx.x;   // 4 elems each; 524288 total
  const int d4 = (idx & 15)*4;
  const int rr = (idx >> 4) & 127;
  const int pb = idx >> 11;                       // 0..255 = qt8*32 + bh
  const int qt8 = pb >> 5, bh = pb & 31;
  const int b = bh >> 4, h = bh & 15;
  const int pr = pb*128 + rr;
  const float s0 = s0b[pr], s1 = s1b[pr];
  const float wn = 1.f/(s0 + s1);
  const float w0 = s0*wn, w1 = s1*wn;
  const size_t ao = ((size_t)(b*SS + (8 + qt8)*128 + rr))*EE + h*DD + d4;
  const size_t po = (size_t)pr*64 + d4;
  ushort4 a = *(const ushort4*)&ab[ao];
  ushort4 p = *(const ushort4*)&pbuf[po];
  ushort4 o;
  o.x = f2bf(w0*bf2f(a.x) + w1*bf2f(p.x));
  o.y = f2bf(w0*bf2f(a.y) + w1*bf2f(p.y));
  o.z = f2bf(w0*bf2f(a.z) + w1*bf2f(p.z));
  o.w = f2bf(w0*bf2f(a.w) + w1*bf2f(p.w));
  *(ushort4*)&ab[ao] = o;
}

extern "C" void kernel_launch(void* const* d_in, const int* in_sizes, int n_in,
                              void* d_out, int out_size, void* d_ws, size_t ws_size,
                              hipStream_t stream){
  const float* x      = (const float*)d_in[0];
  const float* w_attn = (const float*)d_in[1];
  const float* b_attn = (const float*)d_in[2];
  const float* w_proj = (const float*)d_in[3];
  const float* b_proj = (const float*)d_in[4];
  float* out = (float*)d_out;

  ushort* ws   = (ushort*)d_ws;
  ushort* xb   = ws;                           // scratch (x no longer staged here)
  ushort* waT  = xb  + (size_t)MM*EE;          // [3072,1024] bf16 (w_attn^T)
  ushort* wpT  = waT + (size_t)N1*EE;          // [1024,1024] bf16 (w_proj^T)
  ushort* qb_  = wpT + (size_t)EE*EE;          // Q  [B,H,S,64]
  ushort* kb_  = qb_ + (size_t)MM*EE;          // K  [B,H,S,64]
  ushort* vTb  = kb_ + (size_t)MM*EE;          // V^T[B,H,64,S]
  ushort* ab   = vTb + (size_t)MM*EE;          // attn out [B,S,E]
  // split-K scratch, reusing xb (dead) — waT stays live only until attn2.
  ushort* pbuf = xb;                           // 8*32*128*64 bf16 = 4.2 MB
  float*  s0b  = (float*)(pbuf + (size_t)8*32*128*64);
  float*  s1b  = s0b + 8*32*128;

  prep_kernel<<<4096, 256, 0, stream>>>(w_attn, waT, w_proj, wpT);
  gemm_qkv<<<dim3(N1/128, MM/128), 256, 0, stream>>>(x, waT, b_attn, qb_, kb_, vTb, MM, N1, EE);
  attn2<<<dim3(BB*HH, 24), 256, 0, stream>>>(qb_, kb_, vTb, ab, pbuf, s0b, s1b);
  combine_kernel<<<2048, 256, 0, stream>>>(ab, pbuf, s0b, s1b);
  gemm_proj<<<dim3(EE/128, MM/64), 256, 0, stream>>>(ab, wpT, b_proj, out, MM, EE, EE);
}

// Round 22
// 107.972 us; speedup vs baseline: 1.2068x; 1.2068x over previous
//
#include <hip/hip_runtime.h>
#include <hip/hip_bf16.h>

#define BB 2
#define SS 2048
#define EE 1024
#define HH 16
#define DD 64
#define MM (BB*SS)      // 4096
#define N1 (3*EE)       // 3072

typedef __attribute__((ext_vector_type(4))) float f32x4;
typedef __attribute__((ext_vector_type(16))) float f32x16;
typedef __attribute__((ext_vector_type(8))) short bf16x8;
typedef __attribute__((ext_vector_type(4))) unsigned int u32x4;
typedef __attribute__((ext_vector_type(2))) unsigned int u32x2;

__device__ __forceinline__ ushort f2bf(float f){
  union { float f; unsigned u; } v; v.f = f;
  unsigned r = v.u + 0x7fffu + ((v.u >> 16) & 1u);
  return (ushort)(r >> 16);
}

__device__ __forceinline__ float bf2f(ushort u){
  union { unsigned u; float f; } v; v.u = ((unsigned)u) << 16; return v.f;
}

__device__ __forceinline__ unsigned cvt_pk(float a, float b){
  unsigned r; asm("v_cvt_pk_bf16_f32 %0, %1, %2" : "=v"(r) : "v"(a), "v"(b)); return r;
}

__device__ __forceinline__ float exp2_fast(float x){
  float r; asm("v_exp_f32 %0, %1" : "=v"(r) : "v"(x)); return r;
}

// v_permlane32_swap_b32 (lane-half exchange of 32-bit values)
__device__ __forceinline__ u32x2 pl32swap(unsigned a, unsigned b){
  return __builtin_amdgcn_permlane32_swap(a, b, false, false);
}

// async global->LDS, 16B per lane. LDS dest = wave-uniform base + lane*16.
__device__ __forceinline__ void gload16(const void* g, void* l){
  __builtin_amdgcn_global_load_lds(
      (const __attribute__((address_space(1))) unsigned*)g,
      (__attribute__((address_space(3))) unsigned*)l, 16, 0, 0);
}

// ---- fused prep: x->bf16 (blocks 0..4095), w_attn^T (..7167), w_proj^T (..8191)
// NOTE (r21): folding x->bf16 into gemm_qkv's A-staging REGRESSED 39->76us
// (A re-read 24x as fp32 doubled FETCH + reg-staged loads serialize). This
// one-pass conversion amortizes: keep it.
__global__ __launch_bounds__(256) void prep_kernel(const float* __restrict__ x, ushort* __restrict__ xb,
    const float* __restrict__ wa, ushort* __restrict__ waT,
    const float* __restrict__ wp, ushort* __restrict__ wpT){
  __shared__ float t[32][33];
  const int bid = blockIdx.x, tid = threadIdx.x;
  if (bid < 4096){
    int i = bid*256 + tid;
    const float4 f = reinterpret_cast<const float4*>(x)[i];
    ushort4 o; o.x=f2bf(f.x); o.y=f2bf(f.y); o.z=f2bf(f.z); o.w=f2bf(f.w);
    reinterpret_cast<ushort4*>(xb)[i] = o;
  } else {
    const float* in; ushort* out; int N, nx, b;
    if (bid < 7168){ b = bid - 4096; in = wa; out = waT; N = N1; nx = N1/32; }
    else           { b = bid - 7168; in = wp; out = wpT; N = EE; nx = EE/32; }
    const int n0 = (b % nx)*32, k0 = (b / nx)*32;
    const int tx = tid & 31, ty = tid >> 5;
    for (int r = ty; r < 32; r += 8)
      t[r][tx] = in[(size_t)(k0+r)*N + n0 + tx];
    __syncthreads();
    for (int r = ty; r < 32; r += 8)
      out[(size_t)(n0+r)*EE + k0 + tx] = f2bf(t[tx][r]);
  }
}

// ---- QKV GEMM, 128x128 tile, BK=64 + XOR-swizzled LDS (round-12/18 proven).
// NOTE: 256x128 tile REGRESSED (r13, m112); BK=32 ring-3 counted-vmcnt REGRESSED
// (r19); fp32-A conversion-fold REGRESSED (r21). This 2-barrier BK=64 bf16-A
// form is the measured optimum for this kernel.
__global__ __launch_bounds__(256) void gemm_qkv(const ushort* __restrict__ A,
    const ushort* __restrict__ Bt, const float* __restrict__ bias,
    ushort* __restrict__ q_, ushort* __restrict__ k_, ushort* __restrict__ v_,
    int M, int N, int K){
  __shared__ ushort As[128*64];
  __shared__ ushort Bs[128*64];
  const int tid = threadIdx.x;
  const int lane = tid & 63, w = tid >> 6;
  const int nx = gridDim.x;
  const int nwg = nx * gridDim.y;
  const int flat = blockIdx.y*nx + blockIdx.x;
  const int sw = (flat & 7)*(nwg >> 3) + (flat >> 3);
  const int m0 = (sw / nx)*128, n0 = (sw % nx)*128;
  const int wm = (w >> 1)*64, wn = (w & 1)*64;
  const int lr = lane & 15, g4 = lane >> 4;
  const int c0 = w*4;
  const int csr = lane >> 3;
  const int gcb = ((lane & 7) ^ csr)*8;
  const int sw7 = lr & 7;

  f32x4 acc[4][4] = {};
  for (int k0 = 0; k0 < K; k0 += 64){
    #pragma unroll
    for (int i = 0; i < 4; ++i){
      const int c = c0 + i;
      gload16(A  + (size_t)(m0 + c*8 + csr)*K + k0 + gcb, &As[(c*8)*64]);
      gload16(Bt + (size_t)(n0 + c*8 + csr)*K + k0 + gcb, &Bs[(c*8)*64]);
    }
    __syncthreads();
    #pragma unroll
    for (int kk = 0; kk < 2; ++kk){
      bf16x8 af[4], bfr[4];
      #pragma unroll
      for (int m = 0; m < 4; ++m)
        af[m] = *reinterpret_cast<bf16x8*>(&As[(wm + m*16 + lr)*64 + (((kk*4 + g4) ^ sw7)*8)]);
      #pragma unroll
      for (int n = 0; n < 4; ++n)
        bfr[n] = *reinterpret_cast<bf16x8*>(&Bs[(wn + n*16 + lr)*64 + (((kk*4 + g4) ^ sw7)*8)]);
      __builtin_amdgcn_s_setprio(1);
      #pragma unroll
      for (int m = 0; m < 4; ++m)
        #pragma unroll
        for (int n = 0; n < 4; ++n)
          acc[m][n] = __builtin_amdgcn_mfma_f32_16x16x32_bf16(af[m], bfr[n], acc[m][n], 0, 0, 0);
      __builtin_amdgcn_s_setprio(0);
    }
    __syncthreads();
  }
  #pragma unroll
  for (int m = 0; m < 4; ++m){
    #pragma unroll
    for (int n = 0; n < 4; ++n){
      int col = n0 + wn + n*16 + lr;
      float bv = bias[col];
      #pragma unroll
      for (int r = 0; r < 4; ++r){
        int row = m0 + wm + m*16 + (lane >> 4)*4 + r;
        float v = acc[m][n][r] + bv;
        int b = row >> 11, s = row & 2047;
        int h = col / 192, t = col - h*192;
        ushort u = f2bf(v);
        size_t bh = (size_t)(b*HH + h);
        if (t < 64)       q_[(bh*SS + s)*DD + t]        = u;
        else if (t < 128) k_[(bh*SS + s)*DD + (t-64)]   = u;
        else              v_[(bh*DD + (t-128))*SS + s]  = u;
      }
    }
  }
}

// ---- proj GEMM: 64x128 tile, BK=64, XOR-swizzle. 512 blocks -> 2 blocks/CU.
__global__ __launch_bounds__(256) void gemm_proj(const ushort* __restrict__ A,
    const ushort* __restrict__ Bt, const float* __restrict__ bias,
    float* __restrict__ of, int M, int N, int K){
  __shared__ ushort As[64*64];    // 8 KB
  __shared__ ushort Bs[128*64];   // 16 KB
  const int tid = threadIdx.x;
  const int lane = tid & 63, w = tid >> 6;
  const int nx = gridDim.x;                       // 8
  const int nwg = nx * gridDim.y;                 // 512
  const int flat = blockIdx.y*nx + blockIdx.x;
  const int sw = (flat & 7)*(nwg >> 3) + (flat >> 3);
  const int m0 = (sw / nx)*64, n0 = (sw % nx)*128;
  const int lr = lane & 15, g4 = lane >> 4;
  const int csr = lane >> 3;
  const int gcb = ((lane & 7) ^ csr)*8;
  const int sw7 = lr & 7;

  f32x4 acc[4][2] = {};
  for (int k0 = 0; k0 < K; k0 += 64){
    #pragma unroll
    for (int i = 0; i < 2; ++i){                  // A: 8 chunks, 2/wave
      const int c = w*2 + i;
      gload16(A + (size_t)(m0 + c*8 + csr)*K + k0 + gcb, &As[(c*8)*64]);
    }
    #pragma unroll
    for (int i = 0; i < 4; ++i){                  // B: 16 chunks, 4/wave
      const int c = w*4 + i;
      gload16(Bt + (size_t)(n0 + c*8 + csr)*K + k0 + gcb, &Bs[(c*8)*64]);
    }
    __syncthreads();
    #pragma unroll
    for (int kk = 0; kk < 2; ++kk){
      bf16x8 af[4], bfr[2];
      #pragma unroll
      for (int m = 0; m < 4; ++m)
        af[m] = *reinterpret_cast<bf16x8*>(&As[(m*16 + lr)*64 + (((kk*4 + g4) ^ sw7)*8)]);
      #pragma unroll
      for (int n = 0; n < 2; ++n)
        bfr[n] = *reinterpret_cast<bf16x8*>(&Bs[(w*32 + n*16 + lr)*64 + (((kk*4 + g4) ^ sw7)*8)]);
      __builtin_amdgcn_s_setprio(1);
      #pragma unroll
      for (int m = 0; m < 4; ++m)
        #pragma unroll
        for (int n = 0; n < 2; ++n)
          acc[m][n] = __builtin_amdgcn_mfma_f32_16x16x32_bf16(af[m], bfr[n], acc[m][n], 0, 0, 0);
      __builtin_amdgcn_s_setprio(0);
    }
    __syncthreads();
  }
  #pragma unroll
  for (int m = 0; m < 4; ++m){
    #pragma unroll
    for (int n = 0; n < 2; ++n){
      int col = n0 + w*32 + n*16 + lr;
      float bv = bias[col];
      #pragma unroll
      for (int r = 0; r < 4; ++r){
        int row = m0 + m*16 + g4*4 + r;
        of[(size_t)row*N + col] = acc[m][n][r] + bv;
      }
    }
  }
}

// ---- causal flash attention, split-K x2 + no-max softmax, ring-3 + vmcnt(4)
// (round-12/16 proven config; r20 XCD remap kept — neutral-to-positive.)
#define SCL 0.18033688f          /* log2(e)/8 */
__global__ __launch_bounds__(256,3) void attn2(const ushort* __restrict__ Qg,
    const ushort* __restrict__ Kg, const ushort* __restrict__ Vg,
    ushort* __restrict__ aout, ushort* __restrict__ pbuf,
    float* __restrict__ s0b, float* __restrict__ s1b){
  __shared__ __align__(16) ushort Kl[3][64*64];
  __shared__ __align__(16) ushort Vl[3][64*64];
  const int tid = threadIdx.x, lane = tid & 63, wv = tid >> 6;
  // XCD swizzle: flat id -> logical so XCD r (= flat%8) owns bh [4r, 4r+4)
  const int flat = blockIdx.y*32 + blockIdx.x;        // 0..767
  const int logical = (flat & 7)*96 + (flat >> 3);    // bijective (768 = 8*96)
  const int bh = logical / 24;
  const int c  = logical - bh*24;
  int qt, t0, t1, half;
  if (c < 8){ qt = c; t0 = 0; t1 = 2*(c+1); half = -1; }
  else { int i = c - 8; qt = 8 + (i >> 1); int n = qt + 1; half = i & 1;
         t0 = half ? n : 0; t1 = half ? 2*n : n; }
  const int b = bh >> 4, h = bh & 15;
  const int q0 = qt*128;
  const int ql = lane & 31, g = lane >> 5;
  const int qrow = q0 + wv*32 + ql;
  const int qminw = q0 + wv*32;
  const int qmaxw = qminw + 31;

  const ushort* Qp = Qg + ((size_t)bh*SS + qrow)*DD;
  bf16x8 qf[4];
  #pragma unroll
  for (int s = 0; s < 4; ++s)
    qf[s] = *(const bf16x8*)(Qp + s*16 + g*8);

  f32x16 ot[2] = {};
  float sr = 0.f;

  const int csr = lane >> 3;
  const int gcb = ((lane & 7) ^ csr)*8;
  const ushort* Kbase = Kg + (size_t)bh*SS*DD;
  const ushort* Vbase = Vg + (size_t)bh*DD*SS;
  const int nv = (qmaxw >> 6) + 1;
  const int swq = (ql & 7);

  auto stage = [&](int t, int bi){          // 4 loads/wave
    const int k0 = t*64;
    #pragma unroll
    for (int i = 0; i < 2; ++i){
      const int ch = wv*2 + i;
      gload16(Kbase + (size_t)(k0 + ch*8 + csr)*DD + gcb, &Kl[bi][(ch*8)*64]);
      gload16(Vbase + (size_t)(ch*8 + csr)*SS + k0 + gcb, &Vl[bi][(ch*8)*64]);
    }
  };

  auto qk = [&](int t, int bi, f32x16& s0, f32x16& s1){
    const ushort* Kc = &Kl[bi][0];
    f32x16 a0 = {}, a1 = {};
    __builtin_amdgcn_s_setprio(1);
    #pragma unroll
    for (int s = 0; s < 4; ++s){
      bf16x8 kf0 = *(const bf16x8*)&Kc[ ql     *64 + (((2*s + g) ^ swq)*8)];
      bf16x8 kf1 = *(const bf16x8*)&Kc[(32+ql) *64 + (((2*s + g) ^ swq)*8)];
      a0 = __builtin_amdgcn_mfma_f32_32x32x16_bf16(kf0, qf[s], a0, 0, 0, 0);
      a1 = __builtin_amdgcn_mfma_f32_32x32x16_bf16(kf1, qf[s], a1, 0, 0, 0);
    }
    __builtin_amdgcn_s_setprio(0);
    const int k0 = t*64;
    if (k0 + 63 > qminw){
      #pragma unroll
      for (int r = 0; r < 16; ++r){
        int kg0 = k0 + (r & 3) + 8*(r >> 2) + 4*g;
        a0[r] = (kg0 > qrow) ? -1e30f : a0[r];
        a1[r] = (kg0 + 32 > qrow) ? -1e30f : a1[r];
      }
    }
    s0 = a0; s1 = a1;
  };

  auto smpv = [&](int bi, f32x16& s0, f32x16& s1){
    float p[2][16];
    #pragma unroll
    for (int r = 0; r < 16; ++r){
      p[0][r] = exp2_fast(s0[r]*SCL);
      p[1][r] = exp2_fast(s1[r]*SCL);
    }
    float s8[8];
    #pragma unroll
    for (int i = 0; i < 8; ++i)
      s8[i] = (p[0][i] + p[0][i+8]) + (p[1][i] + p[1][i+8]);
    float ts = ((s8[0]+s8[1]) + (s8[2]+s8[3])) + ((s8[4]+s8[5]) + (s8[6]+s8[7]));
    { u32x2 rs = pl32swap(__float_as_uint(ts), __float_as_uint(ts));
      ts = __uint_as_float(rs[0]) + __uint_as_float(rs[1]); }
    sr += ts;

    const ushort* Vc = &Vl[bi][0];
    __builtin_amdgcn_s_setprio(1);
    #pragma unroll
    for (int kf = 0; kf < 2; ++kf){
      #pragma unroll
      for (int s2 = 0; s2 < 2; ++s2){
        const int base = s2*8;
        unsigned u0 = cvt_pk(p[kf][base+0], p[kf][base+1]);
        unsigned u1 = cvt_pk(p[kf][base+2], p[kf][base+3]);
        unsigned u2 = cvt_pk(p[kf][base+4], p[kf][base+5]);
        unsigned u3 = cvt_pk(p[kf][base+6], p[kf][base+7]);
        u32x2 r0 = pl32swap(u0, u2);
        u32x2 r1 = pl32swap(u1, u3);
        union { u32x4 u; bf16x8 hv; } pw;
        pw.u[0] = r0[0]; pw.u[1] = r1[0]; pw.u[2] = r0[1]; pw.u[3] = r1[1];
        const int cbv = 4*kf + 2*s2 + g;
        bf16x8 v0f = *(const bf16x8*)&Vc[ ql     *64 + ((cbv ^ swq)*8)];
        bf16x8 v1f = *(const bf16x8*)&Vc[(32+ql) *64 + ((cbv ^ swq)*8)];
        ot[0] = __builtin_amdgcn_mfma_f32_32x32x16_bf16(v0f, pw.hv, ot[0], 0, 0, 0);
        ot[1] = __builtin_amdgcn_mfma_f32_32x32x16_bf16(v1f, pw.hv, ot[1], 0, 0, 0);
      }
    }
    __builtin_amdgcn_s_setprio(0);
  };

  stage(t0, 0);
  stage(t0 + 1, 1);
  int bi = 0;                               // buffer of tile t: (t - t0) % 3
  for (int t = t0; t < t1; ++t){
    if (t + 1 < t1) { asm volatile("s_waitcnt vmcnt(4)" ::: "memory"); }
    else            { asm volatile("s_waitcnt vmcnt(0)" ::: "memory"); }
    __builtin_amdgcn_s_barrier();
    __builtin_amdgcn_sched_barrier(0);
    if (t + 2 < t1){
      int bs = bi + 2; if (bs >= 3) bs -= 3;
      stage(t + 2, bs);
    }
    if (t < nv){
      f32x16 s0, s1;
      qk(t, bi, s0, s1);
      smpv(bi, s0, s1);
    }
    ++bi; if (bi == 3) bi = 0;
  }

  const float inv = 1.f / sr;
  if (half == 1){
    const int pr = ((qt - 8)*32 + bh)*128 + wv*32 + ql;
    #pragma unroll
    for (int df = 0; df < 2; ++df){
      #pragma unroll
      for (int t = 0; t < 4; ++t){
        ushort4 o4;
        o4.x = f2bf(ot[df][t*4+0]*inv);
        o4.y = f2bf(ot[df][t*4+1]*inv);
        o4.z = f2bf(ot[df][t*4+2]*inv);
        o4.w = f2bf(ot[df][t*4+3]*inv);
        int d = df*32 + 8*t + 4*g;
        *(ushort4*)&pbuf[(size_t)pr*64 + d] = o4;
      }
    }
    if (g == 0) s1b[pr] = sr;
  } else {
    const size_t obase = ((size_t)b*SS + qrow)*EE + h*DD;
    #pragma unroll
    for (int df = 0; df < 2; ++df){
      #pragma unroll
      for (int t = 0; t < 4; ++t){
        ushort4 o4;
        o4.x = f2bf(ot[df][t*4+0]*inv);
        o4.y = f2bf(ot[df][t*4+1]*inv);
        o4.z = f2bf(ot[df][t*4+2]*inv);
        o4.w = f2bf(ot[df][t*4+3]*inv);
        int d = df*32 + 8*t + 4*g;
        *(ushort4*)&aout[obase + d] = o4;
      }
    }
    if (half == 0){
      const int pr = ((qt - 8)*32 + bh)*128 + wv*32 + ql;
      if (g == 0) s0b[pr] = sr;
    }
  }
}

// ---- merge split-K halves: O = (s0*O0 + s1*O1)/(s0+s1) for qt 8..15 ----
__global__ __launch_bounds__(256) void combine_kernel(ushort* __restrict__ ab,
    const ushort* __restrict__ pbuf, const float* __restrict__ s0b,
    const float* __restrict__ s1b){
  const int idx = blockIdx.x*256 + threadIdx.x;   // 4 elems each; 524288 total
  const int d4 = (idx & 15)*4;
  const int rr = (idx >> 4) & 127;
  const int pb = idx >> 11;                       // 0..255 = qt8*32 + bh
  const int qt8 = pb >> 5, bh = pb & 31;
  const int b = bh >> 4, h = bh & 15;
  const int pr = pb*128 + rr;
  const float s0 = s0b[pr], s1 = s1b[pr];
  const float wn = 1.f/(s0 + s1);
  const float w0 = s0*wn, w1 = s1*wn;
  const size_t ao = ((size_t)(b*SS + (8 + qt8)*128 + rr))*EE + h*DD + d4;
  const size_t po = (size_t)pr*64 + d4;
  ushort4 a = *(const ushort4*)&ab[ao];
  ushort4 p = *(const ushort4*)&pbuf[po];
  ushort4 o;
  o.x = f2bf(w0*bf2f(a.x) + w1*bf2f(p.x));
  o.y = f2bf(w0*bf2f(a.y) + w1*bf2f(p.y));
  o.z = f2bf(w0*bf2f(a.z) + w1*bf2f(p.z));
  o.w = f2bf(w0*bf2f(a.w) + w1*bf2f(p.w));
  *(ushort4*)&ab[ao] = o;
}

extern "C" void kernel_launch(void* const* d_in, const int* in_sizes, int n_in,
                              void* d_out, int out_size, void* d_ws, size_t ws_size,
                              hipStream_t stream){
  const float* x      = (const float*)d_in[0];
  const float* w_attn = (const float*)d_in[1];
  const float* b_attn = (const float*)d_in[2];
  const float* w_proj = (const float*)d_in[3];
  const float* b_proj = (const float*)d_in[4];
  float* out = (float*)d_out;

  ushort* ws   = (ushort*)d_ws;
  ushort* xb   = ws;                           // [4096,1024] bf16
  ushort* waT  = xb  + (size_t)MM*EE;          // [3072,1024] bf16 (w_attn^T)
  ushort* wpT  = waT + (size_t)N1*EE;          // [1024,1024] bf16 (w_proj^T)
  ushort* qb_  = wpT + (size_t)EE*EE;          // Q  [B,H,S,64]
  ushort* kb_  = qb_ + (size_t)MM*EE;          // K  [B,H,S,64]
  ushort* vTb  = kb_ + (size_t)MM*EE;          // V^T[B,H,64,S]
  ushort* ab   = vTb + (size_t)MM*EE;          // attn out [B,S,E]
  // split-K scratch, reusing regions dead after gemm_qkv:
  ushort* pbuf = xb;                           // 8*32*128*64 bf16 = 4.2 MB
  float*  s0b  = (float*)waT;                  // 32768 floats
  float*  s1b  = s0b + 8*32*128;

  prep_kernel<<<8192, 256, 0, stream>>>(x, xb, w_attn, waT, w_proj, wpT);
  gemm_qkv<<<dim3(N1/128, MM/128), 256, 0, stream>>>(xb, waT, b_attn, qb_, kb_, vTb, MM, N1, EE);
  attn2<<<dim3(BB*HH, 24), 256, 0, stream>>>(qb_, kb_, vTb, ab, pbuf, s0b, s1b);
  combine_kernel<<<2048, 256, 0, stream>>>(ab, pbuf, s0b, s1b);
  gemm_proj<<<dim3(EE/128, MM/64), 256, 0, stream>>>(ab, wpT, b_proj, out, MM, EE, EE);
}

// Round 23
// 102.855 us; speedup vs baseline: 1.2669x; 1.0497x over previous
//
#include <hip/hip_runtime.h>
#include <hip/hip_bf16.h>

#define BB 2
#define SS 2048
#define EE 1024
#define HH 16
#define DD 64
#define MM (BB*SS)      // 4096
#define N1 (3*EE)       // 3072

typedef __attribute__((ext_vector_type(4))) float f32x4;
typedef __attribute__((ext_vector_type(16))) float f32x16;
typedef __attribute__((ext_vector_type(8))) short bf16x8;
typedef __attribute__((ext_vector_type(4))) unsigned int u32x4;
typedef __attribute__((ext_vector_type(2))) unsigned int u32x2;

__device__ __forceinline__ ushort f2bf(float f){
  union { float f; unsigned u; } v; v.f = f;
  unsigned r = v.u + 0x7fffu + ((v.u >> 16) & 1u);
  return (ushort)(r >> 16);
}

__device__ __forceinline__ float bf2f(ushort u){
  union { unsigned u; float f; } v; v.u = ((unsigned)u) << 16; return v.f;
}

__device__ __forceinline__ unsigned cvt_pk(float a, float b){
  unsigned r; asm("v_cvt_pk_bf16_f32 %0, %1, %2" : "=v"(r) : "v"(a), "v"(b)); return r;
}

__device__ __forceinline__ float exp2_fast(float x){
  float r; asm("v_exp_f32 %0, %1" : "=v"(r) : "v"(x)); return r;
}

// v_permlane32_swap_b32 (lane-half exchange of 32-bit values)
__device__ __forceinline__ u32x2 pl32swap(unsigned a, unsigned b){
  return __builtin_amdgcn_permlane32_swap(a, b, false, false);
}

// async global->LDS, 16B per lane. LDS dest = wave-uniform base + lane*16.
__device__ __forceinline__ void gload16(const void* g, void* l){
  __builtin_amdgcn_global_load_lds(
      (const __attribute__((address_space(1))) unsigned*)g,
      (__attribute__((address_space(3))) unsigned*)l, 16, 0, 0);
}

// ---- fused prep: x->bf16 (blocks 0..4095), w_attn^T (..7167), w_proj^T (..8191)
// NOTE (r21): folding x->bf16 into gemm_qkv REGRESSED 39->76us. Keep one-pass.
__global__ __launch_bounds__(256) void prep_kernel(const float* __restrict__ x, ushort* __restrict__ xb,
    const float* __restrict__ wa, ushort* __restrict__ waT,
    const float* __restrict__ wp, ushort* __restrict__ wpT){
  __shared__ float t[32][33];
  const int bid = blockIdx.x, tid = threadIdx.x;
  if (bid < 4096){
    int i = bid*256 + tid;
    const float4 f = reinterpret_cast<const float4*>(x)[i];
    ushort4 o; o.x=f2bf(f.x); o.y=f2bf(f.y); o.z=f2bf(f.z); o.w=f2bf(f.w);
    reinterpret_cast<ushort4*>(xb)[i] = o;
  } else {
    const float* in; ushort* out; int N, nx, b;
    if (bid < 7168){ b = bid - 4096; in = wa; out = waT; N = N1; nx = N1/32; }
    else           { b = bid - 7168; in = wp; out = wpT; N = EE; nx = EE/32; }
    const int n0 = (b % nx)*32, k0 = (b / nx)*32;
    const int tx = tid & 31, ty = tid >> 5;
    for (int r = ty; r < 32; r += 8)
      t[r][tx] = in[(size_t)(k0+r)*N + n0 + tx];
    __syncthreads();
    for (int r = ty; r < 32; r += 8)
      out[(size_t)(n0+r)*EE + k0 + tx] = f2bf(t[tx][r]);
  }
}

// ---- QKV GEMM, 128x128 tile, BK=64 + XOR-swizzled LDS (round-12/18 proven loop).
// NEW (r23): epilogue routes C through LDS ([128][136] bf16, chunk-swizzled
// pc = (col>>3)^((row>>3)&7)) and emits 16B stores: each 64-col half of the
// tile lies entirely in one of q/k/v (192,128 share 64-alignment), and the
// 128 rows lie in one batch. q/k: per-row contiguous 64 -> ds_read_b128 +
// dwordx4. v: per-col contiguous rows (V^T) -> 8 scalar LDS reads + dwordx4.
// Replaces 64 scalar 2B global stores/thread with 8 vector stores.
__global__ __launch_bounds__(256) void gemm_qkv(const ushort* __restrict__ A,
    const ushort* __restrict__ Bt, const float* __restrict__ bias,
    ushort* __restrict__ q_, ushort* __restrict__ k_, ushort* __restrict__ v_,
    int M, int N, int K){
  __shared__ ushort smem[17408];          // As[8192] | Bs[8192]; reused as C[128][136]
  ushort* As = smem;
  ushort* Bs = smem + 8192;
  const int tid = threadIdx.x;
  const int lane = tid & 63, w = tid >> 6;
  const int nx = gridDim.x;
  const int nwg = nx * gridDim.y;
  const int flat = blockIdx.y*nx + blockIdx.x;
  const int sw = (flat & 7)*(nwg >> 3) + (flat >> 3);
  const int m0 = (sw / nx)*128, n0 = (sw % nx)*128;
  const int wm = (w >> 1)*64, wn = (w & 1)*64;
  const int lr = lane & 15, g4 = lane >> 4;
  const int c0 = w*4;
  const int csr = lane >> 3;
  const int gcb = ((lane & 7) ^ csr)*8;
  const int sw7 = lr & 7;

  f32x4 acc[4][4] = {};
  for (int k0 = 0; k0 < K; k0 += 64){
    #pragma unroll
    for (int i = 0; i < 4; ++i){
      const int c = c0 + i;
      gload16(A  + (size_t)(m0 + c*8 + csr)*K + k0 + gcb, &As[(c*8)*64]);
      gload16(Bt + (size_t)(n0 + c*8 + csr)*K + k0 + gcb, &Bs[(c*8)*64]);
    }
    __syncthreads();
    #pragma unroll
    for (int kk = 0; kk < 2; ++kk){
      bf16x8 af[4], bfr[4];
      #pragma unroll
      for (int m = 0; m < 4; ++m)
        af[m] = *reinterpret_cast<bf16x8*>(&As[(wm + m*16 + lr)*64 + (((kk*4 + g4) ^ sw7)*8)]);
      #pragma unroll
      for (int n = 0; n < 4; ++n)
        bfr[n] = *reinterpret_cast<bf16x8*>(&Bs[(wn + n*16 + lr)*64 + (((kk*4 + g4) ^ sw7)*8)]);
      __builtin_amdgcn_s_setprio(1);
      #pragma unroll
      for (int m = 0; m < 4; ++m)
        #pragma unroll
        for (int n = 0; n < 4; ++n)
          acc[m][n] = __builtin_amdgcn_mfma_f32_16x16x32_bf16(af[m], bfr[n], acc[m][n], 0, 0, 0);
      __builtin_amdgcn_s_setprio(0);
    }
    __syncthreads();
  }
  // -------- epilogue: C -> LDS (swizzled) -> coalesced 16B stores --------
  ushort* C = smem;                       // [128 rows][pitch 136]
  #pragma unroll
  for (int m = 0; m < 4; ++m){
    #pragma unroll
    for (int n = 0; n < 4; ++n){
      const int col = wn + n*16 + lr;
      const float bv = bias[n0 + col];
      const int rb = wm + m*16 + g4*4;
      #pragma unroll
      for (int r = 0; r < 4; ++r){
        const int row = rb + r;
        const int pc = (col >> 3) ^ ((row >> 3) & 7);
        C[row*136 + pc*8 + (col & 7)] = f2bf(acc[m][n][r] + bv);
      }
    }
  }
  __syncthreads();
  const int bq = m0 >> 11, sb0 = m0 & 2047;
  const int th = tid >> 7, tt = tid & 127;  // half (wave-uniform), id in half
  const int cb = n0 + th*64;                // half's first global col
  const int hb = cb % 192;                  // 0 -> q, 64 -> k, 128 -> v
  const int hh = cb / 192;                  // head (uniform within half)
  const size_t bh = (size_t)(bq*HH + hh);
  if (hb < 128){
    ushort* P = (hb ? k_ : q_) + (bh*SS + sb0)*DD;
    const int rg = tt >> 3, j = tt & 7;
    #pragma unroll
    for (int k = 0; k < 8; ++k){
      const int row = rg*8 + k;
      const int pc = (th*8 + j) ^ (rg & 7);     // row>>3 == rg for k<8
      u32x4 vv = *(u32x4*)&C[row*136 + pc*8];
      *(u32x4*)&P[(size_t)row*DD + j*8] = vv;
    }
  } else {
    ushort* P = v_ + bh*DD*SS;
    const int col = tt >> 1, rcb = (tt & 1)*8;
    #pragma unroll
    for (int k = 0; k < 8; ++k){
      const int rc = rcb + k;
      const int pc = (th*8 + (col >> 3)) ^ (rc & 7);
      union { u32x4 u; ushort us[8]; } vv;
      #pragma unroll
      for (int i = 0; i < 8; ++i)
        vv.us[i] = C[(rc*8 + i)*136 + pc*8 + (col & 7)];
      *(u32x4*)&P[(size_t)col*SS + sb0 + rc*8] = vv.u;
    }
  }
}

// ---- proj GEMM: 64x128 tile, BK=64, XOR-swizzle. 512 blocks -> 2 blocks/CU.
__global__ __launch_bounds__(256) void gemm_proj(const ushort* __restrict__ A,
    const ushort* __restrict__ Bt, const float* __restrict__ bias,
    float* __restrict__ of, int M, int N, int K){
  __shared__ ushort As[64*64];    // 8 KB
  __shared__ ushort Bs[128*64];   // 16 KB
  const int tid = threadIdx.x;
  const int lane = tid & 63, w = tid >> 6;
  const int nx = gridDim.x;                       // 8
  const int nwg = nx * gridDim.y;                 // 512
  const int flat = blockIdx.y*nx + blockIdx.x;
  const int sw = (flat & 7)*(nwg >> 3) + (flat >> 3);
  const int m0 = (sw / nx)*64, n0 = (sw % nx)*128;
  const int lr = lane & 15, g4 = lane >> 4;
  const int csr = lane >> 3;
  const int gcb = ((lane & 7) ^ csr)*8;
  const int sw7 = lr & 7;

  f32x4 acc[4][2] = {};
  for (int k0 = 0; k0 < K; k0 += 64){
    #pragma unroll
    for (int i = 0; i < 2; ++i){                  // A: 8 chunks, 2/wave
      const int c = w*2 + i;
      gload16(A + (size_t)(m0 + c*8 + csr)*K + k0 + gcb, &As[(c*8)*64]);
    }
    #pragma unroll
    for (int i = 0; i < 4; ++i){                  // B: 16 chunks, 4/wave
      const int c = w*4 + i;
      gload16(Bt + (size_t)(n0 + c*8 + csr)*K + k0 + gcb, &Bs[(c*8)*64]);
    }
    __syncthreads();
    #pragma unroll
    for (int kk = 0; kk < 2; ++kk){
      bf16x8 af[4], bfr[2];
      #pragma unroll
      for (int m = 0; m < 4; ++m)
        af[m] = *reinterpret_cast<bf16x8*>(&As[(m*16 + lr)*64 + (((kk*4 + g4) ^ sw7)*8)]);
      #pragma unroll
      for (int n = 0; n < 2; ++n)
        bfr[n] = *reinterpret_cast<bf16x8*>(&Bs[(w*32 + n*16 + lr)*64 + (((kk*4 + g4) ^ sw7)*8)]);
      __builtin_amdgcn_s_setprio(1);
      #pragma unroll
      for (int m = 0; m < 4; ++m)
        #pragma unroll
        for (int n = 0; n < 2; ++n)
          acc[m][n] = __builtin_amdgcn_mfma_f32_16x16x32_bf16(af[m], bfr[n], acc[m][n], 0, 0, 0);
      __builtin_amdgcn_s_setprio(0);
    }
    __syncthreads();
  }
  #pragma unroll
  for (int m = 0; m < 4; ++m){
    #pragma unroll
    for (int n = 0; n < 2; ++n){
      int col = n0 + w*32 + n*16 + lr;
      float bv = bias[col];
      #pragma unroll
      for (int r = 0; r < 4; ++r){
        int row = m0 + m*16 + g4*4 + r;
        of[(size_t)row*N + col] = acc[m][n][r] + bv;
      }
    }
  }
}

// ---- causal flash attention, split-K x2 + no-max softmax, ring-3 + vmcnt(4)
// (round-12/16 proven config; r20 XCD remap kept — neutral-to-positive.)
#define SCL 0.18033688f          /* log2(e)/8 */
__global__ __launch_bounds__(256,3) void attn2(const ushort* __restrict__ Qg,
    const ushort* __restrict__ Kg, const ushort* __restrict__ Vg,
    ushort* __restrict__ aout, ushort* __restrict__ pbuf,
    float* __restrict__ s0b, float* __restrict__ s1b){
  __shared__ __align__(16) ushort Kl[3][64*64];
  __shared__ __align__(16) ushort Vl[3][64*64];
  const int tid = threadIdx.x, lane = tid & 63, wv = tid >> 6;
  const int flat = blockIdx.y*32 + blockIdx.x;        // 0..767
  const int logical = (flat & 7)*96 + (flat >> 3);    // bijective (768 = 8*96)
  const int bh = logical / 24;
  const int c  = logical - bh*24;
  int qt, t0, t1, half;
  if (c < 8){ qt = c; t0 = 0; t1 = 2*(c+1); half = -1; }
  else { int i = c - 8; qt = 8 + (i >> 1); int n = qt + 1; half = i & 1;
         t0 = half ? n : 0; t1 = half ? 2*n : n; }
  const int b = bh >> 4, h = bh & 15;
  const int q0 = qt*128;
  const int ql = lane & 31, g = lane >> 5;
  const int qrow = q0 + wv*32 + ql;
  const int qminw = q0 + wv*32;
  const int qmaxw = qminw + 31;

  const ushort* Qp = Qg + ((size_t)bh*SS + qrow)*DD;
  bf16x8 qf[4];
  #pragma unroll
  for (int s = 0; s < 4; ++s)
    qf[s] = *(const bf16x8*)(Qp + s*16 + g*8);

  f32x16 ot[2] = {};
  float sr = 0.f;

  const int csr = lane >> 3;
  const int gcb = ((lane & 7) ^ csr)*8;
  const ushort* Kbase = Kg + (size_t)bh*SS*DD;
  const ushort* Vbase = Vg + (size_t)bh*DD*SS;
  const int nv = (qmaxw >> 6) + 1;
  const int swq = (ql & 7);

  auto stage = [&](int t, int bi){          // 4 loads/wave
    const int k0 = t*64;
    #pragma unroll
    for (int i = 0; i < 2; ++i){
      const int ch = wv*2 + i;
      gload16(Kbase + (size_t)(k0 + ch*8 + csr)*DD + gcb, &Kl[bi][(ch*8)*64]);
      gload16(Vbase + (size_t)(ch*8 + csr)*SS + k0 + gcb, &Vl[bi][(ch*8)*64]);
    }
  };

  auto qk = [&](int t, int bi, f32x16& s0, f32x16& s1){
    const ushort* Kc = &Kl[bi][0];
    f32x16 a0 = {}, a1 = {};
    __builtin_amdgcn_s_setprio(1);
    #pragma unroll
    for (int s = 0; s < 4; ++s){
      bf16x8 kf0 = *(const bf16x8*)&Kc[ ql     *64 + (((2*s + g) ^ swq)*8)];
      bf16x8 kf1 = *(const bf16x8*)&Kc[(32+ql) *64 + (((2*s + g) ^ swq)*8)];
      a0 = __builtin_amdgcn_mfma_f32_32x32x16_bf16(kf0, qf[s], a0, 0, 0, 0);
      a1 = __builtin_amdgcn_mfma_f32_32x32x16_bf16(kf1, qf[s], a1, 0, 0, 0);
    }
    __builtin_amdgcn_s_setprio(0);
    const int k0 = t*64;
    if (k0 + 63 > qminw){
      #pragma unroll
      for (int r = 0; r < 16; ++r){
        int kg0 = k0 + (r & 3) + 8*(r >> 2) + 4*g;
        a0[r] = (kg0 > qrow) ? -1e30f : a0[r];
        a1[r] = (kg0 + 32 > qrow) ? -1e30f : a1[r];
      }
    }
    s0 = a0; s1 = a1;
  };

  auto smpv = [&](int bi, f32x16& s0, f32x16& s1){
    float p[2][16];
    #pragma unroll
    for (int r = 0; r < 16; ++r){
      p[0][r] = exp2_fast(s0[r]*SCL);
      p[1][r] = exp2_fast(s1[r]*SCL);
    }
    float s8[8];
    #pragma unroll
    for (int i = 0; i < 8; ++i)
      s8[i] = (p[0][i] + p[0][i+8]) + (p[1][i] + p[1][i+8]);
    float ts = ((s8[0]+s8[1]) + (s8[2]+s8[3])) + ((s8[4]+s8[5]) + (s8[6]+s8[7]));
    { u32x2 rs = pl32swap(__float_as_uint(ts), __float_as_uint(ts));
      ts = __uint_as_float(rs[0]) + __uint_as_float(rs[1]); }
    sr += ts;

    const ushort* Vc = &Vl[bi][0];
    __builtin_amdgcn_s_setprio(1);
    #pragma unroll
    for (int kf = 0; kf < 2; ++kf){
      #pragma unroll
      for (int s2 = 0; s2 < 2; ++s2){
        const int base = s2*8;
        unsigned u0 = cvt_pk(p[kf][base+0], p[kf][base+1]);
        unsigned u1 = cvt_pk(p[kf][base+2], p[kf][base+3]);
        unsigned u2 = cvt_pk(p[kf][base+4], p[kf][base+5]);
        unsigned u3 = cvt_pk(p[kf][base+6], p[kf][base+7]);
        u32x2 r0 = pl32swap(u0, u2);
        u32x2 r1 = pl32swap(u1, u3);
        union { u32x4 u; bf16x8 hv; } pw;
        pw.u[0] = r0[0]; pw.u[1] = r1[0]; pw.u[2] = r0[1]; pw.u[3] = r1[1];
        const int cbv = 4*kf + 2*s2 + g;
        bf16x8 v0f = *(const bf16x8*)&Vc[ ql     *64 + ((cbv ^ swq)*8)];
        bf16x8 v1f = *(const bf16x8*)&Vc[(32+ql) *64 + ((cbv ^ swq)*8)];
        ot[0] = __builtin_amdgcn_mfma_f32_32x32x16_bf16(v0f, pw.hv, ot[0], 0, 0, 0);
        ot[1] = __builtin_amdgcn_mfma_f32_32x32x16_bf16(v1f, pw.hv, ot[1], 0, 0, 0);
      }
    }
    __builtin_amdgcn_s_setprio(0);
  };

  stage(t0, 0);
  stage(t0 + 1, 1);
  int bi = 0;                               // buffer of tile t: (t - t0) % 3
  for (int t = t0; t < t1; ++t){
    if (t + 1 < t1) { asm volatile("s_waitcnt vmcnt(4)" ::: "memory"); }
    else            { asm volatile("s_waitcnt vmcnt(0)" ::: "memory"); }
    __builtin_amdgcn_s_barrier();
    __builtin_amdgcn_sched_barrier(0);
    if (t + 2 < t1){
      int bs = bi + 2; if (bs >= 3) bs -= 3;
      stage(t + 2, bs);
    }
    if (t < nv){
      f32x16 s0, s1;
      qk(t, bi, s0, s1);
      smpv(bi, s0, s1);
    }
    ++bi; if (bi == 3) bi = 0;
  }

  const float inv = 1.f / sr;
  if (half == 1){
    const int pr = ((qt - 8)*32 + bh)*128 + wv*32 + ql;
    #pragma unroll
    for (int df = 0; df < 2; ++df){
      #pragma unroll
      for (int t = 0; t < 4; ++t){
        ushort4 o4;
        o4.x = f2bf(ot[df][t*4+0]*inv);
        o4.y = f2bf(ot[df][t*4+1]*inv);
        o4.z = f2bf(ot[df][t*4+2]*inv);
        o4.w = f2bf(ot[df][t*4+3]*inv);
        int d = df*32 + 8*t + 4*g;
        *(ushort4*)&pbuf[(size_t)pr*64 + d] = o4;
      }
    }
    if (g == 0) s1b[pr] = sr;
  } else {
    const size_t obase = ((size_t)b*SS + qrow)*EE + h*DD;
    #pragma unroll
    for (int df = 0; df < 2; ++df){
      #pragma unroll
      for (int t = 0; t < 4; ++t){
        ushort4 o4;
        o4.x = f2bf(ot[df][t*4+0]*inv);
        o4.y = f2bf(ot[df][t*4+1]*inv);
        o4.z = f2bf(ot[df][t*4+2]*inv);
        o4.w = f2bf(ot[df][t*4+3]*inv);
        int d = df*32 + 8*t + 4*g;
        *(ushort4*)&aout[obase + d] = o4;
      }
    }
    if (half == 0){
      const int pr = ((qt - 8)*32 + bh)*128 + wv*32 + ql;
      if (g == 0) s0b[pr] = sr;
    }
  }
}

// ---- merge split-K halves: O = (s0*O0 + s1*O1)/(s0+s1) for qt 8..15 ----
__global__ __launch_bounds__(256) void combine_kernel(ushort* __restrict__ ab,
    const ushort* __restrict__ pbuf, const float* __restrict__ s0b,
    const float* __restrict__ s1b){
  const int idx = blockIdx.x*256 + threadIdx.x;   // 4 elems each; 524288 total
  const int d4 = (idx & 15)*4;
  const int rr = (idx >> 4) & 127;
  const int pb = idx >> 11;                       // 0..255 = qt8*32 + bh
  const int qt8 = pb >> 5, bh = pb & 31;
  const int b = bh >> 4, h = bh & 15;
  const int pr = pb*128 + rr;
  const float s0 = s0b[pr], s1 = s1b[pr];
  const float wn = 1.f/(s0 + s1);
  const float w0 = s0*wn, w1 = s1*wn;
  const size_t ao = ((size_t)(b*SS + (8 + qt8)*128 + rr))*EE + h*DD + d4;
  const size_t po = (size_t)pr*64 + d4;
  ushort4 a = *(const ushort4*)&ab[ao];
  ushort4 p = *(const ushort4*)&pbuf[po];
  ushort4 o;
  o.x = f2bf(w0*bf2f(a.x) + w1*bf2f(p.x));
  o.y = f2bf(w0*bf2f(a.y) + w1*bf2f(p.y));
  o.z = f2bf(w0*bf2f(a.z) + w1*bf2f(p.z));
  o.w = f2bf(w0*bf2f(a.w) + w1*bf2f(p.w));
  *(ushort4*)&ab[ao] = o;
}

extern "C" void kernel_launch(void* const* d_in, const int* in_sizes, int n_in,
                              void* d_out, int out_size, void* d_ws, size_t ws_size,
                              hipStream_t stream){
  const float* x      = (const float*)d_in[0];
  const float* w_attn = (const float*)d_in[1];
  const float* b_attn = (const float*)d_in[2];
  const float* w_proj = (const float*)d_in[3];
  const float* b_proj = (const float*)d_in[4];
  float* out = (float*)d_out;

  ushort* ws   = (ushort*)d_ws;
  ushort* xb   = ws;                           // [4096,1024] bf16
  ushort* waT  = xb  + (size_t)MM*EE;          // [3072,1024] bf16 (w_attn^T)
  ushort* wpT  = waT + (size_t)N1*EE;          // [1024,1024] bf16 (w_proj^T)
  ushort* qb_  = wpT + (size_t)EE*EE;          // Q  [B,H,S,64]
  ushort* kb_  = qb_ + (size_t)MM*EE;          // K  [B,H,S,64]
  ushort* vTb  = kb_ + (size_t)MM*EE;          // V^T[B,H,64,S]
  ushort* ab   = vTb + (size_t)MM*EE;          // attn out [B,S,E]
  // split-K scratch, reusing regions dead after gemm_qkv:
  ushort* pbuf = xb;                           // 8*32*128*64 bf16 = 4.2 MB
  float*  s0b  = (float*)waT;                  // 32768 floats
  float*  s1b  = s0b + 8*32*128;

  prep_kernel<<<8192, 256, 0, stream>>>(x, xb, w_attn, waT, w_proj, wpT);
  gemm_qkv<<<dim3(N1/128, MM/128), 256, 0, stream>>>(xb, waT, b_attn, qb_, kb_, vTb, MM, N1, EE);
  attn2<<<dim3(BB*HH, 24), 256, 0, stream>>>(qb_, kb_, vTb, ab, pbuf, s0b, s1b);
  combine_kernel<<<2048, 256, 0, stream>>>(ab, pbuf, s0b, s1b);
  gemm_proj<<<dim3(EE/128, MM/64), 256, 0, stream>>>(ab, wpT, b_proj, out, MM, EE, EE);
}